// Round 4
// baseline (2864.523 us; speedup 1.0000x reference)
//
#include <hip/hip_runtime.h>
#include <stdint.h>

#define Bdim 1024
#define Tdim 512
#define DIN  64
#define DOUT 32
#define DZ   32
#define DH   128
#define Msamp 2
#define NWG  (Bdim / Msamp)   // 512 workgroups -> 2 blocks/CU
#define NTHR 512
#define SP   136              // padded row stride (bf16 elems)

using s16x8 = __attribute__((ext_vector_type(8))) short;   // 8 x bf16
using f32x4 = __attribute__((ext_vector_type(4))) float;

#define MFMA(a, b, c) __builtin_amdgcn_mfma_f32_16x16x32_bf16((a), (b), (c), 0, 0, 0)

// ---------------- threefry2x32 (JAX/Random123, 20 rounds) ----------------
__host__ __device__ inline void tf2x32(unsigned k0, unsigned k1, unsigned c0, unsigned c1,
                                       unsigned &o0, unsigned &o1) {
  unsigned ks2 = k0 ^ k1 ^ 0x1BD11BDAu;
  unsigned x0 = c0 + k0, x1 = c1 + k1;
#define TFR(r) { x0 += x1; x1 = (x1 << (r)) | (x1 >> (32 - (r))); x1 ^= x0; }
  TFR(13) TFR(15) TFR(26) TFR(6)
  x0 += k1;  x1 += ks2 + 1u;
  TFR(17) TFR(29) TFR(16) TFR(24)
  x0 += ks2; x1 += k0 + 2u;
  TFR(13) TFR(15) TFR(26) TFR(6)
  x0 += k0;  x1 += k1 + 3u;
  TFR(17) TFR(29) TFR(16) TFR(24)
  x0 += k1;  x1 += ks2 + 4u;
  TFR(13) TFR(15) TFR(26) TFR(6)
  x0 += ks2; x1 += k0 + 5u;
#undef TFR
  o0 = x0; o1 = x1;
}

__device__ inline float erfinv_xla(float x) {
  float w = -log1pf(-x * x);
  float p;
  if (w < 5.0f) {
    w -= 2.5f;
    p = 2.81022636e-08f;
    p = fmaf(p, w, 3.43273939e-07f);
    p = fmaf(p, w, -3.5233877e-06f);
    p = fmaf(p, w, -4.39150654e-06f);
    p = fmaf(p, w, 0.00021858087f);
    p = fmaf(p, w, -0.00125372503f);
    p = fmaf(p, w, -0.00417768164f);
    p = fmaf(p, w, 0.246640727f);
    p = fmaf(p, w, 1.50140941f);
  } else {
    w = sqrtf(w) - 3.0f;
    p = -0.000200214257f;
    p = fmaf(p, w, 0.000100950558f);
    p = fmaf(p, w, 0.00134934322f);
    p = fmaf(p, w, -0.00367342844f);
    p = fmaf(p, w, 0.00573950773f);
    p = fmaf(p, w, -0.0076224613f);
    p = fmaf(p, w, 0.00943887047f);
    p = fmaf(p, w, 1.00167406f);
    p = fmaf(p, w, 2.83297682f);
  }
  return p * x;
}

__device__ inline float bits_to_normal(unsigned bits) {
  float f = __uint_as_float((bits >> 9) | 0x3f800000u) - 1.0f;
  float u = f * 2.0f - 0.99999994f;
  u = fmaxf(u, -0.99999994f);
  return 1.41421356f * erfinv_xla(u);
}

// partitionable threefry: bits[i] = x0 ^ x1 of cipher(key, (0, i))
__device__ inline float jax_normal(unsigned k0, unsigned k1, unsigned idx) {
  unsigned o0, o1;
  tf2x32(k0, k1, 0u, idx, o0, o1);
  return bits_to_normal(o0 ^ o1);
}

// ---------------- small helpers ----------------
__device__ inline float clampf(float v) { return fminf(fmaxf(v, -10.0f), 2.0f); }
__device__ inline float tanh_fast(float v) {
  float e = __expf(2.0f * v);
  return 1.0f - __fdividef(2.0f, e + 1.0f);
}
__device__ inline short f2bf_rne(float x) {   // single v_cvt_pk_bf16_f32 (RNE)
  unsigned u;
  asm("v_cvt_pk_bf16_f32 %0, %1, %2" : "=v"(u) : "v"(x), "v"(x));
  return (short)(u & 0xffffu);
}

// one MFMA B-fragment (16 cols x 32 k) of fp32 W (K x N row-major) as bf16
__device__ inline s16x8 load_frag(const float* __restrict__ W, int N, int kt, int nt, int lane) {
  int k0 = kt * 32 + ((lane >> 4) << 3);
  int n  = nt * 16 + (lane & 15);
  s16x8 f;
#pragma unroll
  for (int e = 0; e < 8; ++e) {
    float x = W[(size_t)(k0 + e) * N + n];
    unsigned u = __float_as_uint(x);
    u = (u + 0x7fffu + ((u >> 16) & 1u)) >> 16;
    f[e] = (short)u;
  }
  return f;
}

// A-fragment pointer: rows 0..Msamp-1 real, rows >=Msamp -> shared zero page (broadcast)
__device__ inline const s16x8* afp(const short* buf, const short* zp, int lane) {
  int r = lane & 15;
  const short* p = (r < Msamp) ? (buf + r * SP) : zp;
  return (const s16x8*)(p + ((lane >> 4) << 3));
}

// spread 16x16 D-tile (valid rows 0..1, held by lanes 0-15 regs 0-1) across 32 lanes:
// lane l gets D[(l>>4)&1][l&15]; works identically for lanes 32-63.
__device__ __forceinline__ float spread2(int pi, f32x4 c, int lane) {
  int v0 = __builtin_amdgcn_ds_bpermute(pi, __float_as_int(c[0]));
  int v1 = __builtin_amdgcn_ds_bpermute(pi, __float_as_int(c[1]));
  return __int_as_float((lane & 16) ? v1 : v0);
}

// ---------------- main persistent kernel ----------------
__global__ __launch_bounds__(NTHR, 4) void dssm_main(
    const float* __restrict__ gx, const float* __restrict__ gy,
    const float* __restrict__ pW1, const float* __restrict__ pb1,
    const float* __restrict__ pW2, const float* __restrict__ pb2,
    const float* __restrict__ pW3, const float* __restrict__ pb3,
    const float* __restrict__ qW1, const float* __restrict__ qb1,
    const float* __restrict__ qW2, const float* __restrict__ qb2,
    const float* __restrict__ qW3, const float* __restrict__ qb3,
    const float* __restrict__ eW1, const float* __restrict__ eb1,
    const float* __restrict__ eW2, const float* __restrict__ eb2,
    const float* __restrict__ eW3, const float* __restrict__ eb3,
    const float* __restrict__ z0mu, const float* __restrict__ z0lv,
    float* __restrict__ gout, float* __restrict__ gws,
    unsigned ka0, unsigned ka1, unsigned kb0, unsigned kb1)
{
  // activations: 2 real rows per buffer; zero-page serves MFMA rows 2..15
  __shared__ __align__(16) short in_pq[2 * SP];                     // [z32|x64|y32]
  __shared__ __align__(16) short hpa[2 * SP], hqa[2 * SP], hea[2 * SP];
  __shared__ __align__(16) short hpb[2 * SP], hqb[2 * SP], heb[2 * SP];
  __shared__ __align__(16) short zpage[128];
  __shared__ __align__(16) s16x8 wlds[48 * 64];                     // 48 KiB weight frags
  __shared__ float out_p[2][64], out_q[2][64], emit_o[2][64];
  __shared__ float epsb[8][64];                                     // 8-step eps ring

  const int tid  = threadIdx.x;
  const int w    = tid >> 6;
  const int lane = tid & 63;
  const int wg   = blockIdx.x;
  const int base = wg * Msamp;
  const int col  = lane & 15;
  const int sRow = (lane >> 4) & 1;
  const int pi   = col << 2;                    // bpermute byte index (spread)
  const int pi32 = ((lane ^ 32) & 63) << 2;     // bpermute swap halves

  // ---- register weight fragments (same for all waves: 20 frags = 80 VGPR) ----
  s16x8 fP1[3], fQ1[4], fE1, fP2[4], fQ2[4], fT3[4];
#pragma unroll
  for (int kt = 0; kt < 3; ++kt) fP1[kt] = load_frag(pW1, DH, kt, w, lane);
#pragma unroll
  for (int kt = 0; kt < 4; ++kt) fQ1[kt] = load_frag(qW1, DH, kt, w, lane);
  fE1 = load_frag(eW1, DH, 0, w, lane);
#pragma unroll
  for (int kt = 0; kt < 4; ++kt) fP2[kt] = load_frag(pW2, DH, kt, w, lane);
#pragma unroll
  for (int kt = 0; kt < 4; ++kt) fQ2[kt] = load_frag(qW2, DH, kt, w, lane);
  {
    const float* W3 = (w < 4) ? eW3 : ((w < 6) ? qW3 : pW3);
    int nt3 = (w < 4) ? w : ((w < 6) ? (w - 4) : (w - 6));
#pragma unroll
    for (int kt = 0; kt < 4; ++kt) fT3[kt] = load_frag(W3, 2 * DOUT, kt, nt3, lane);
  }

  // ---- LDS weight fragments: emit W2 (32 frags) + lv-halves of q/p heads (8+8) ----
  for (int i = tid; i < 48 * 64; i += NTHR) {
    int fid = i >> 6, ln = i & 63;
    const float* W; int nt, kt = fid & 3;
    if (fid < 32)      { W = eW2; nt = fid >> 2;            wlds[i] = load_frag(W, DH, kt, nt, ln); }
    else if (fid < 40) { W = qW3; nt = 2 + ((fid - 32) >> 2); wlds[i] = load_frag(W, 64, kt, nt, ln); }
    else               { W = pW3; nt = 2 + ((fid - 40) >> 2); wlds[i] = load_frag(W, 64, kt, nt, ln); }
  }

  // ---- hoisted per-lane biases ----
  float b1  = (lane < 32) ? pb1[w * 16 + col] : qb1[w * 16 + col];
  float b1e = eb1[w * 16 + col];
  float b2  = (lane < 32) ? pb2[w * 16 + col] : qb2[w * 16 + col];
  float b2e = eb2[w * 16 + col];
  float b3;
  if (w < 4)      b3 = eb3[w * 16 + col];
  else if (w < 6) b3 = (lane < 32) ? qb3[(w - 4) * 16 + col] : qb3[32 + (w - 4) * 16 + col];
  else            b3 = (lane < 32) ? pb3[(w - 6) * 16 + col] : pb3[32 + (w - 6) * 16 + col];

  // ---- hoisted LDS pointers ----
  short* wp1  = ((lane < 32) ? hpa : hqa) + sRow * SP + w * 16 + col;
  short* wp1e = hea + sRow * SP + w * 16 + col;
  short* wp2  = ((lane < 32) ? hpb : hqb) + sRow * SP + w * 16 + col;
  short* wp2e = heb + sRow * SP + w * 16 + col;
  float* wp3;
  if (w < 4)      wp3 = &emit_o[sRow][w * 16 + col];
  else if (w < 6) wp3 = &out_q[sRow][((lane >= 32) ? 32 : 0) + (w - 4) * 16 + col];
  else            wp3 = &out_p[sRow][((lane >= 32) ? 32 : 0) + (w - 6) * 16 + col];
  short* zwp = &in_pq[sRow * SP + ((w - 4) & 3) * 16 + col];
  const int epsi = sRow * 32 + ((w - 4) & 3) * 16 + col;

  const s16x8* aIn = afp(in_pq, zpage, lane);
  const s16x8* aPa = afp(hpa, zpage, lane);
  const s16x8* aQa = afp(hqa, zpage, lane);
  const s16x8* aEa = afp(hea, zpage, lane);
  const s16x8* aPb = afp(hpb, zpage, lane);
  const s16x8* aQb = afp(hqb, zpage, lane);
  const s16x8* aEb = afp(heb, zpage, lane);
  const s16x8* aH  = (w < 6) ? aQb : aPb;
  const s16x8* wE2 = &wlds[lane] + (w * 4) * 64;                       // emit W2 frags
  const s16x8* wH3 = &wlds[lane] + (((w < 6) ? 32 + ((w - 4) & 3) * 4 : 40 + (w - 6) * 4)) * 64;

  // ---- prologue: zero page, t=0 inputs, z0 ----
  if (tid < 128) zpage[tid] = 0;
  float yq0 = 0.f, yq1 = 0.f, yq2 = 0.f, xv = 0.f, yv = 0.f;
  if (tid < 128) {
    int s = tid >> 6, j = tid & 63;
    in_pq[s * SP + 32 + j] = f2bf_rne(gx[((size_t)(base + s) * Tdim) * DIN + j]);
  }
  if (w == 1) {
    int s = lane >> 5, j = lane & 31;
    yq2 = gy[((size_t)(base + s) * Tdim) * DOUT + j];
    in_pq[s * SP + 96 + j] = f2bf_rne(yq2);
  }
  if (tid < 64) {
    int s = tid >> 5, zd = tid & 31;
    float e0 = jax_normal(ka0, ka1, (unsigned)(base + s) * DZ + zd);
    float lv = clampf(z0lv[zd]);
    in_pq[s * SP + zd] = f2bf_rne(z0mu[zd] + __expf(0.5f * lv) * e0);
  }
  __syncthreads();

  float kl_acc = 0.f, nll_acc = 0.f;

#pragma unroll 1
  for (int t = 0; t <= Tdim; ++t) {
    // ======== PHASE 1: L1 (prior+post+emit) | eps batch | prefetch | KL(t-1) ========
    if ((t & 7) == 0 && t < Tdim) {
      unsigned idx = (unsigned)(t + w) * (unsigned)(Bdim * DZ)
                   + (unsigned)(base + (lane >> 5)) * DZ + (lane & 31);
      epsb[w][lane] = jax_normal(kb0, kb1, idx);
    }
    if (t + 1 < Tdim) {
      if (w == 2 || w == 3) xv = gx[((size_t)(base + (w - 2)) * Tdim + (t + 1)) * DIN + lane];
      if (w == 1)           yv = gy[((size_t)(base + (lane >> 5)) * Tdim + (t + 1)) * DOUT + (lane & 31)];
    }
    f32x4 cP = {0.f, 0.f, 0.f, 0.f}, cQ = {0.f, 0.f, 0.f, 0.f}, cE = {0.f, 0.f, 0.f, 0.f};
    cP = MFMA(aIn[0], fP1[0], cP); cP = MFMA(aIn[4], fP1[1], cP); cP = MFMA(aIn[8], fP1[2], cP);
    cQ = MFMA(aIn[0], fQ1[0], cQ); cQ = MFMA(aIn[4], fQ1[1], cQ);
    cQ = MFMA(aIn[8], fQ1[2], cQ); cQ = MFMA(aIn[12], fQ1[3], cQ);
    cE = MFMA(aIn[0], fE1, cE);
    if (w == 0 && t >= 1) {
      int s = lane >> 5, zd = lane & 31;
      float mq = out_q[s][zd], lq = clampf(out_q[s][32 + zd]);
      float mp = out_p[s][zd], lp = clampf(out_p[s][32 + zd]);
      float dm = mq - mp;
      kl_acc += lp - lq + (__expf(lq) + dm * dm) / (__expf(lp) + 1e-12f);
    }
    {
      float vP = spread2(pi, cP, lane), vQ = spread2(pi, cQ, lane);
      float vE = spread2(pi, cE, lane);
      float v  = (lane >= 32) ? vQ : vP;
      *wp1 = f2bf_rne(tanh_fast(v + b1));
      if (lane < 32) *wp1e = f2bf_rne(tanh_fast(vE + b1e));
    }
    __syncthreads();

    // ======== PHASE 2: L2 (prior+post+emit[LDS frags]) | NLL(t-2) ========
    f32x4 dP = {0.f, 0.f, 0.f, 0.f}, dQ = {0.f, 0.f, 0.f, 0.f}, dE = {0.f, 0.f, 0.f, 0.f};
#pragma unroll
    for (int kt = 0; kt < 4; ++kt) {
      dP = MFMA(aPa[kt * 4], fP2[kt], dP);
      dQ = MFMA(aQa[kt * 4], fQ2[kt], dQ);
      dE = MFMA(aEa[kt * 4], wE2[kt * 64], dE);
    }
    if (w == 1 && t >= 2) {
      int s = lane >> 5, j = lane & 31;
      float mu = emit_o[s][j], lv = clampf(emit_o[s][32 + j]);
      float d = yq0 - mu;
      nll_acc += lv + d * d * __expf(-lv);
    }
    {
      float vP = spread2(pi, dP, lane), vQ = spread2(pi, dQ, lane);
      float vE = spread2(pi, dE, lane);
      float v  = (lane >= 32) ? vQ : vP;
      *wp2 = f2bf_rne(tanh_fast(v + b2));
      if (lane < 32) *wp2e = f2bf_rne(tanh_fast(vE + b2e));
    }
    __syncthreads();

    // ======== PHASE 3: heads + emit L3 + in-reg z-sample + x/y commit ========
    if (w < 4) {
      f32x4 e = {0.f, 0.f, 0.f, 0.f};
#pragma unroll
      for (int kt = 0; kt < 4; ++kt) e = MFMA(aEb[kt * 4], fT3[kt], e);
      float v = spread2(pi, e, lane) + b3;
      if (lane < 32) {
        *wp3 = v;
        if (w < 2 && t >= 1)
          gout[((size_t)(base + sRow) * Tdim + (t - 1)) * DOUT + w * 16 + col] = v;
      }
    } else {
      f32x4 cM = {0.f, 0.f, 0.f, 0.f}, cL = {0.f, 0.f, 0.f, 0.f};
#pragma unroll
      for (int kt = 0; kt < 4; ++kt) {
        cM = MFMA(aH[kt * 4], fT3[kt], cM);
        cL = MFMA(aH[kt * 4], wH3[kt * 64], cL);
      }
      float vM = spread2(pi, cM, lane), vL = spread2(pi, cL, lane);
      float v  = ((lane >= 32) ? vL : vM) + b3;
      *wp3 = v;
      // q-head waves sample z_t in-register (lv pulled from sibling half-wave)
      float vswap = __int_as_float(__builtin_amdgcn_ds_bpermute(pi32, __float_as_int(v)));
      if (w < 6 && lane < 32) {
        float lvq = clampf(vswap);
        float z = v + __expf(0.5f * lvq) * epsb[t & 7][epsi];
        *zwp = f2bf_rne(z);
      }
    }
    if (t + 1 < Tdim) {
      if (w == 2 || w == 3) in_pq[(w - 2) * SP + 32 + lane] = f2bf_rne(xv);
      if (w == 1)           in_pq[(lane >> 5) * SP + 96 + (lane & 31)] = f2bf_rne(yv);
    }
    if (w == 1) { yq0 = yq1; yq1 = yq2; yq2 = yv; }
    __syncthreads();
  }

  // final NLL (step 511; emit_o from last iteration, visible after loop barrier)
  if (w == 1) {
    int s = lane >> 5, j = lane & 31;
    float mu = emit_o[s][j], lv = clampf(emit_o[s][32 + j]);
    float d = yq0 - mu;
    nll_acc += lv + d * d * __expf(-lv);
  }

  // per-WG reduction: wave1 holds nll, wave0 holds kl
  float vn = nll_acc, vk = kl_acc;
#pragma unroll
  for (int o = 32; o > 0; o >>= 1) { vn += __shfl_down(vn, o, 64); vk += __shfl_down(vk, o, 64); }
  if (tid == 64) gws[wg] = vn;
  if (tid == 0)  gws[NWG + wg] = vk;
}

// ---------------- finalize ----------------
__global__ void dssm_fin(const float* __restrict__ gws, float* __restrict__ gout) {
  __shared__ float sb[16];
  int tid = threadIdx.x;   // 512
  int w = tid >> 6, lane = tid & 63;
  float vn = gws[tid], vk = gws[NWG + tid];
#pragma unroll
  for (int o = 32; o > 0; o >>= 1) { vn += __shfl_down(vn, o, 64); vk += __shfl_down(vk, o, 64); }
  if (lane == 0) { sb[w] = vn; sb[8 + w] = vk; }
  __syncthreads();
  if (tid == 0) {
    float sn = 0.f, sk = 0.f;
#pragma unroll
    for (int i = 0; i < 8; ++i) { sn += sb[i]; sk += sb[8 + i]; }
    const float inv = 1.0f / (float)((size_t)Bdim * Tdim);
    float nll = 0.5f * (sn * inv + (float)DOUT * 1.8378770664093453f);
    float kl  = 0.5f * (sk * inv - (float)DZ);
    size_t o0 = (size_t)Bdim * Tdim * DOUT;
    gout[o0 + 0] = nll + kl;
    gout[o0 + 1] = nll;
    gout[o0 + 2] = kl;
  }
}

extern "C" void kernel_launch(void* const* d_in, const int* in_sizes, int n_in,
                              void* d_out, int out_size, void* d_ws, size_t ws_size,
                              hipStream_t stream) {
  (void)in_sizes; (void)n_in; (void)out_size; (void)ws_size;
  const float* gx  = (const float*)d_in[0];
  const float* gy  = (const float*)d_in[1];
  const float* pW1 = (const float*)d_in[2];  const float* pb1 = (const float*)d_in[3];
  const float* pW2 = (const float*)d_in[4];  const float* pb2 = (const float*)d_in[5];
  const float* pW3 = (const float*)d_in[6];  const float* pb3 = (const float*)d_in[7];
  const float* qW1 = (const float*)d_in[8];  const float* qb1 = (const float*)d_in[9];
  const float* qW2 = (const float*)d_in[10]; const float* qb2 = (const float*)d_in[11];
  const float* qW3 = (const float*)d_in[12]; const float* qb3 = (const float*)d_in[13];
  const float* eW1 = (const float*)d_in[14]; const float* eb1 = (const float*)d_in[15];
  const float* eW2 = (const float*)d_in[16]; const float* eb2 = (const float*)d_in[17];
  const float* eW3 = (const float*)d_in[18]; const float* eb3 = (const float*)d_in[19];
  const float* z0mu = (const float*)d_in[20];
  const float* z0lv = (const float*)d_in[21];
  float* gout = (float*)d_out;
  float* gws  = (float*)d_ws;

  unsigned ka0, ka1, kb0, kb1;
  tf2x32(0u, 42u, 0u, 0u, ka0, ka1);   // fold_in(key(42), 0) -> eps0 key
  tf2x32(0u, 42u, 0u, 1u, kb0, kb1);   // fold_in(key(42), 1) -> eps key

  dssm_main<<<NWG, NTHR, 0, stream>>>(gx, gy,
      pW1, pb1, pW2, pb2, pW3, pb3,
      qW1, qb1, qW2, qb2, qW3, qb3,
      eW1, eb1, eW2, eb2, eW3, eb3,
      z0mu, z0lv, gout, gws, ka0, ka1, kb0, kb1);
  dssm_fin<<<1, 512, 0, stream>>>(gws, gout);
}

// Round 5
// 2835.852 us; speedup vs baseline: 1.0101x; 1.0101x over previous
//
#include <hip/hip_runtime.h>
#include <stdint.h>

#define Bdim 1024
#define Tdim 512
#define DIN  64
#define DOUT 32
#define DZ   32
#define DH   128
#define Msamp 2
#define NWG  (Bdim / Msamp)   // 512 workgroups -> 2 blocks/CU
#define NTHR 512
#define SP   136              // padded row stride (bf16 elems)

using s16x8 = __attribute__((ext_vector_type(8))) short;   // 8 x bf16
using f32x4 = __attribute__((ext_vector_type(4))) float;

#define MFMA(a, b, c) __builtin_amdgcn_mfma_f32_16x16x32_bf16((a), (b), (c), 0, 0, 0)

// ---------------- threefry2x32 (JAX/Random123, 20 rounds) ----------------
__host__ __device__ inline void tf2x32(unsigned k0, unsigned k1, unsigned c0, unsigned c1,
                                       unsigned &o0, unsigned &o1) {
  unsigned ks2 = k0 ^ k1 ^ 0x1BD11BDAu;
  unsigned x0 = c0 + k0, x1 = c1 + k1;
#define TFR(r) { x0 += x1; x1 = (x1 << (r)) | (x1 >> (32 - (r))); x1 ^= x0; }
  TFR(13) TFR(15) TFR(26) TFR(6)
  x0 += k1;  x1 += ks2 + 1u;
  TFR(17) TFR(29) TFR(16) TFR(24)
  x0 += ks2; x1 += k0 + 2u;
  TFR(13) TFR(15) TFR(26) TFR(6)
  x0 += k0;  x1 += k1 + 3u;
  TFR(17) TFR(29) TFR(16) TFR(24)
  x0 += k1;  x1 += ks2 + 4u;
  TFR(13) TFR(15) TFR(26) TFR(6)
  x0 += ks2; x1 += k0 + 5u;
#undef TFR
  o0 = x0; o1 = x1;
}

__device__ inline float erfinv_xla(float x) {
  float w = -log1pf(-x * x);
  float p;
  if (w < 5.0f) {
    w -= 2.5f;
    p = 2.81022636e-08f;
    p = fmaf(p, w, 3.43273939e-07f);
    p = fmaf(p, w, -3.5233877e-06f);
    p = fmaf(p, w, -4.39150654e-06f);
    p = fmaf(p, w, 0.00021858087f);
    p = fmaf(p, w, -0.00125372503f);
    p = fmaf(p, w, -0.00417768164f);
    p = fmaf(p, w, 0.246640727f);
    p = fmaf(p, w, 1.50140941f);
  } else {
    w = sqrtf(w) - 3.0f;
    p = -0.000200214257f;
    p = fmaf(p, w, 0.000100950558f);
    p = fmaf(p, w, 0.00134934322f);
    p = fmaf(p, w, -0.00367342844f);
    p = fmaf(p, w, 0.00573950773f);
    p = fmaf(p, w, -0.0076224613f);
    p = fmaf(p, w, 0.00943887047f);
    p = fmaf(p, w, 1.00167406f);
    p = fmaf(p, w, 2.83297682f);
  }
  return p * x;
}

__device__ inline float bits_to_normal(unsigned bits) {
  float f = __uint_as_float((bits >> 9) | 0x3f800000u) - 1.0f;
  float u = f * 2.0f - 0.99999994f;
  u = fmaxf(u, -0.99999994f);
  return 1.41421356f * erfinv_xla(u);
}

// partitionable threefry: bits[i] = x0 ^ x1 of cipher(key, (0, i))
__device__ inline float jax_normal(unsigned k0, unsigned k1, unsigned idx) {
  unsigned o0, o1;
  tf2x32(k0, k1, 0u, idx, o0, o1);
  return bits_to_normal(o0 ^ o1);
}

// ---------------- small helpers ----------------
__device__ inline float clampf(float v) { return fminf(fmaxf(v, -10.0f), 2.0f); }
__device__ inline float tanh_fast(float v) {
  float e = __expf(2.0f * v);
  return 1.0f - __fdividef(2.0f, e + 1.0f);
}
__device__ inline short f2bf_rne(float x) {   // single v_cvt_pk_bf16_f32 (RNE)
  unsigned u;
  asm("v_cvt_pk_bf16_f32 %0, %1, %2" : "=v"(u) : "v"(x), "v"(x));
  return (short)(u & 0xffffu);
}

// one MFMA B-fragment (16 cols x 32 k) of fp32 W (K x N row-major) as bf16
__device__ inline s16x8 load_frag(const float* __restrict__ W, int N, int kt, int nt, int lane) {
  int k0 = kt * 32 + ((lane >> 4) << 3);
  int n  = nt * 16 + (lane & 15);
  s16x8 f;
#pragma unroll
  for (int e = 0; e < 8; ++e) {
    float x = W[(size_t)(k0 + e) * N + n];
    unsigned u = __float_as_uint(x);
    u = (u + 0x7fffu + ((u >> 16) & 1u)) >> 16;
    f[e] = (short)u;
  }
  return f;
}

// A-fragment pointer: rows 0..Msamp-1 real, rows >=Msamp -> shared zero page (broadcast)
__device__ inline const s16x8* afp(const short* buf, const short* zp, int lane) {
  int r = lane & 15;
  const short* p = (r < Msamp) ? (buf + r * SP) : zp;
  return (const s16x8*)(p + ((lane >> 4) << 3));
}

// spread 16x16 D-tile (valid rows 0..1, held by lanes 0-15 regs 0-1) across 32 lanes:
// lane l gets D[(l>>4)&1][l&15]; works identically for lanes 32-63.
__device__ __forceinline__ float spread2(int pi, f32x4 c, int lane) {
  int v0 = __builtin_amdgcn_ds_bpermute(pi, __float_as_int(c[0]));
  int v1 = __builtin_amdgcn_ds_bpermute(pi, __float_as_int(c[1]));
  return __int_as_float((lane & 16) ? v1 : v0);
}

// ---------------- main persistent kernel ----------------
__global__ __launch_bounds__(NTHR, 4) void dssm_main(
    const float* __restrict__ gx, const float* __restrict__ gy,
    const float* __restrict__ pW1, const float* __restrict__ pb1,
    const float* __restrict__ pW2, const float* __restrict__ pb2,
    const float* __restrict__ pW3, const float* __restrict__ pb3,
    const float* __restrict__ qW1, const float* __restrict__ qb1,
    const float* __restrict__ qW2, const float* __restrict__ qb2,
    const float* __restrict__ qW3, const float* __restrict__ qb3,
    const float* __restrict__ eW1, const float* __restrict__ eb1,
    const float* __restrict__ eW2, const float* __restrict__ eb2,
    const float* __restrict__ eW3, const float* __restrict__ eb3,
    const float* __restrict__ z0mu, const float* __restrict__ z0lv,
    float* __restrict__ gout, float* __restrict__ gws,
    unsigned ka0, unsigned ka1, unsigned kb0, unsigned kb1)
{
  // activations: 2 real rows per buffer; zero-page serves MFMA rows 2..15
  __shared__ __align__(16) short in_pq[2 * SP];                     // [z32|x64|y32]
  __shared__ __align__(16) short hpa[2 * SP], hqa[2 * SP], hea[2 * SP];
  __shared__ __align__(16) short hpb[2 * SP], hqb[2 * SP], heb[2 * SP];
  __shared__ __align__(16) short zpage[128];
  __shared__ __align__(16) s16x8 wlds[48 * 64];                     // 48 KiB weight frags
  __shared__ float out_p[2][64], out_q[2][64], emit_o[2][64];
  __shared__ float epsb[8][64];                                     // 8-step eps ring

  const int tid  = threadIdx.x;
  const int w    = tid >> 6;
  const int lane = tid & 63;
  const int wg   = blockIdx.x;
  const int base = wg * Msamp;
  const int col  = lane & 15;
  const int sRow = (lane >> 4) & 1;
  const int pi   = col << 2;                    // bpermute byte index (spread)
  const int pi32 = ((lane ^ 32) & 63) << 2;     // bpermute swap halves

  // ---- register weight fragments (same for all waves: 20 frags = 80 VGPR) ----
  s16x8 fP1[3], fQ1[4], fE1, fP2[4], fQ2[4], fT3[4];
#pragma unroll
  for (int kt = 0; kt < 3; ++kt) fP1[kt] = load_frag(pW1, DH, kt, w, lane);
#pragma unroll
  for (int kt = 0; kt < 4; ++kt) fQ1[kt] = load_frag(qW1, DH, kt, w, lane);
  fE1 = load_frag(eW1, DH, 0, w, lane);
#pragma unroll
  for (int kt = 0; kt < 4; ++kt) fP2[kt] = load_frag(pW2, DH, kt, w, lane);
#pragma unroll
  for (int kt = 0; kt < 4; ++kt) fQ2[kt] = load_frag(qW2, DH, kt, w, lane);
  {
    const float* W3 = (w < 4) ? eW3 : ((w < 6) ? qW3 : pW3);
    int nt3 = (w < 4) ? w : ((w < 6) ? (w - 4) : (w - 6));
#pragma unroll
    for (int kt = 0; kt < 4; ++kt) fT3[kt] = load_frag(W3, 2 * DOUT, kt, nt3, lane);
  }

  // ---- LDS weight fragments: emit W2 (32 frags) + lv-halves of q/p heads (8+8) ----
  for (int i = tid; i < 48 * 64; i += NTHR) {
    int fid = i >> 6, ln = i & 63;
    const float* W; int nt, kt = fid & 3;
    if (fid < 32)      { W = eW2; nt = fid >> 2;            wlds[i] = load_frag(W, DH, kt, nt, ln); }
    else if (fid < 40) { W = qW3; nt = 2 + ((fid - 32) >> 2); wlds[i] = load_frag(W, 64, kt, nt, ln); }
    else               { W = pW3; nt = 2 + ((fid - 40) >> 2); wlds[i] = load_frag(W, 64, kt, nt, ln); }
  }

  // ---- hoisted per-lane biases ----
  float b1  = (lane < 32) ? pb1[w * 16 + col] : qb1[w * 16 + col];
  float b1e = eb1[w * 16 + col];
  float b2  = (lane < 32) ? pb2[w * 16 + col] : qb2[w * 16 + col];
  float b2e = eb2[w * 16 + col];
  float b3;
  if (w < 4)      b3 = eb3[w * 16 + col];
  else if (w < 6) b3 = (lane < 32) ? qb3[(w - 4) * 16 + col] : qb3[32 + (w - 4) * 16 + col];
  else            b3 = (lane < 32) ? pb3[(w - 6) * 16 + col] : pb3[32 + (w - 6) * 16 + col];

  // ---- hoisted LDS pointers ----
  short* wp1  = ((lane < 32) ? hpa : hqa) + sRow * SP + w * 16 + col;
  short* wp1e = hea + sRow * SP + w * 16 + col;
  short* wp2  = ((lane < 32) ? hpb : hqb) + sRow * SP + w * 16 + col;
  short* wp2e = heb + sRow * SP + w * 16 + col;
  float* wp3;
  if (w < 4)      wp3 = &emit_o[sRow][w * 16 + col];
  else if (w < 6) wp3 = &out_q[sRow][((lane >= 32) ? 32 : 0) + (w - 4) * 16 + col];
  else            wp3 = &out_p[sRow][((lane >= 32) ? 32 : 0) + (w - 6) * 16 + col];
  short* zwp = &in_pq[sRow * SP + ((w - 4) & 3) * 16 + col];
  const int epsi = sRow * 32 + ((w - 4) & 3) * 16 + col;

  const s16x8* aIn = afp(in_pq, zpage, lane);
  const s16x8* aPa = afp(hpa, zpage, lane);
  const s16x8* aQa = afp(hqa, zpage, lane);
  const s16x8* aEa = afp(hea, zpage, lane);
  const s16x8* aPb = afp(hpb, zpage, lane);
  const s16x8* aQb = afp(hqb, zpage, lane);
  const s16x8* aEb = afp(heb, zpage, lane);
  const s16x8* aH  = (w < 6) ? aQb : aPb;
  const s16x8* wE2 = &wlds[lane] + (w * 4) * 64;                       // emit W2 frags
  const s16x8* wH3 = &wlds[lane] + (((w < 6) ? 32 + ((w - 4) & 3) * 4 : 40 + (w - 6) * 4)) * 64;

  // ---- prologue: zero page, t=0 inputs, z0 ----
  if (tid < 128) zpage[tid] = 0;
  float yq0 = 0.f, yq1 = 0.f, yq2 = 0.f, xv = 0.f, yv = 0.f;
  if (tid < 128) {
    int s = tid >> 6, j = tid & 63;
    in_pq[s * SP + 32 + j] = f2bf_rne(gx[((size_t)(base + s) * Tdim) * DIN + j]);
  }
  if (w == 1) {
    int s = lane >> 5, j = lane & 31;
    yq2 = gy[((size_t)(base + s) * Tdim) * DOUT + j];
    in_pq[s * SP + 96 + j] = f2bf_rne(yq2);
  }
  if (tid < 64) {
    int s = tid >> 5, zd = tid & 31;
    float e0 = jax_normal(ka0, ka1, (unsigned)(base + s) * DZ + zd);
    float lv = clampf(z0lv[zd]);
    in_pq[s * SP + zd] = f2bf_rne(z0mu[zd] + __expf(0.5f * lv) * e0);
  }
  __syncthreads();

  float kl_acc = 0.f, nll_acc = 0.f;

#pragma unroll 1
  for (int t = 0; t <= Tdim; ++t) {
    // ======== PHASE 1: L1 (prior+post+emit) | eps batch | prefetch | KL(t-1) ========
    if ((t & 7) == 0 && t < Tdim) {
      unsigned idx = (unsigned)(t + w) * (unsigned)(Bdim * DZ)
                   + (unsigned)(base + (lane >> 5)) * DZ + (lane & 31);
      epsb[w][lane] = jax_normal(kb0, kb1, idx);
    }
    if (t + 1 < Tdim) {
      if (w == 2 || w == 3) xv = gx[((size_t)(base + (w - 2)) * Tdim + (t + 1)) * DIN + lane];
      if (w == 1)           yv = gy[((size_t)(base + (lane >> 5)) * Tdim + (t + 1)) * DOUT + (lane & 31)];
    }
    f32x4 cP = {0.f, 0.f, 0.f, 0.f}, cQ = {0.f, 0.f, 0.f, 0.f}, cE = {0.f, 0.f, 0.f, 0.f};
    cP = MFMA(aIn[0], fP1[0], cP); cP = MFMA(aIn[4], fP1[1], cP); cP = MFMA(aIn[8], fP1[2], cP);
    cQ = MFMA(aIn[0], fQ1[0], cQ); cQ = MFMA(aIn[4], fQ1[1], cQ);
    cQ = MFMA(aIn[8], fQ1[2], cQ); cQ = MFMA(aIn[12], fQ1[3], cQ);
    cE = MFMA(aIn[0], fE1, cE);
    if (w == 0 && t >= 1) {
      int s = lane >> 5, zd = lane & 31;
      float mq = out_q[s][zd], lq = clampf(out_q[s][32 + zd]);
      float mp = out_p[s][zd], lp = clampf(out_p[s][32 + zd]);
      float dm = mq - mp;
      kl_acc += lp - lq + (__expf(lq) + dm * dm) / (__expf(lp) + 1e-12f);
    }
    {
      float vP = spread2(pi, cP, lane), vQ = spread2(pi, cQ, lane);
      float vE = spread2(pi, cE, lane);
      float v  = (lane >= 32) ? vQ : vP;
      *wp1 = f2bf_rne(tanh_fast(v + b1));
      if (lane < 32) *wp1e = f2bf_rne(tanh_fast(vE + b1e));
    }
    __syncthreads();

    // ======== PHASE 2: L2 (prior+post+emit[LDS frags]) | NLL(t-2) ========
    f32x4 dP = {0.f, 0.f, 0.f, 0.f}, dQ = {0.f, 0.f, 0.f, 0.f}, dE = {0.f, 0.f, 0.f, 0.f};
#pragma unroll
    for (int kt = 0; kt < 4; ++kt) {
      dP = MFMA(aPa[kt * 4], fP2[kt], dP);
      dQ = MFMA(aQa[kt * 4], fQ2[kt], dQ);
      dE = MFMA(aEa[kt * 4], wE2[kt * 64], dE);
    }
    if (w == 1 && t >= 2) {
      int s = lane >> 5, j = lane & 31;
      float mu = emit_o[s][j], lv = clampf(emit_o[s][32 + j]);
      float d = yq0 - mu;
      nll_acc += lv + d * d * __expf(-lv);
    }
    {
      float vP = spread2(pi, dP, lane), vQ = spread2(pi, dQ, lane);
      float vE = spread2(pi, dE, lane);
      float v  = (lane >= 32) ? vQ : vP;
      *wp2 = f2bf_rne(tanh_fast(v + b2));
      if (lane < 32) *wp2e = f2bf_rne(tanh_fast(vE + b2e));
    }
    __syncthreads();

    // ======== PHASE 3: heads + emit L3 + in-reg z-sample + x/y commit ========
    if (w < 4) {
      f32x4 e = {0.f, 0.f, 0.f, 0.f};
#pragma unroll
      for (int kt = 0; kt < 4; ++kt) e = MFMA(aEb[kt * 4], fT3[kt], e);
      float v = spread2(pi, e, lane) + b3;
      if (lane < 32) {
        *wp3 = v;
        if (w < 2 && t >= 1)
          gout[((size_t)(base + sRow) * Tdim + (t - 1)) * DOUT + w * 16 + col] = v;
      }
    } else {
      f32x4 cM = {0.f, 0.f, 0.f, 0.f}, cL = {0.f, 0.f, 0.f, 0.f};
#pragma unroll
      for (int kt = 0; kt < 4; ++kt) {
        cM = MFMA(aH[kt * 4], fT3[kt], cM);
        cL = MFMA(aH[kt * 4], wH3[kt * 64], cL);
      }
      float vM = spread2(pi, cM, lane), vL = spread2(pi, cL, lane);
      float v  = ((lane >= 32) ? vL : vM) + b3;
      *wp3 = v;
      // q-head waves sample z_t in-register (lv pulled from sibling half-wave)
      float vswap = __int_as_float(__builtin_amdgcn_ds_bpermute(pi32, __float_as_int(v)));
      if (w < 6 && lane < 32) {
        float lvq = clampf(vswap);
        float z = v + __expf(0.5f * lvq) * epsb[t & 7][epsi];
        *zwp = f2bf_rne(z);
      }
    }
    if (t + 1 < Tdim) {
      if (w == 2 || w == 3) in_pq[(w - 2) * SP + 32 + lane] = f2bf_rne(xv);
      if (w == 1)           in_pq[(lane >> 5) * SP + 96 + (lane & 31)] = f2bf_rne(yv);
    }
    if (w == 1) { yq0 = yq1; yq1 = yq2; yq2 = yv; }
    __syncthreads();
  }

  // final NLL (step 511; emit_o from last iteration, visible after loop barrier)
  if (w == 1) {
    int s = lane >> 5, j = lane & 31;
    float mu = emit_o[s][j], lv = clampf(emit_o[s][32 + j]);
    float d = yq0 - mu;
    nll_acc += lv + d * d * __expf(-lv);
  }

  // per-WG reduction: wave1 holds nll, wave0 holds kl
  float vn = nll_acc, vk = kl_acc;
#pragma unroll
  for (int o = 32; o > 0; o >>= 1) { vn += __shfl_down(vn, o, 64); vk += __shfl_down(vk, o, 64); }
  if (tid == 64) gws[wg] = vn;
  if (tid == 0)  gws[NWG + wg] = vk;
}

// ---------------- finalize ----------------
__global__ void dssm_fin(const float* __restrict__ gws, float* __restrict__ gout) {
  __shared__ float sb[16];
  int tid = threadIdx.x;   // 512
  int w = tid >> 6, lane = tid & 63;
  float vn = gws[tid], vk = gws[NWG + tid];
#pragma unroll
  for (int o = 32; o > 0; o >>= 1) { vn += __shfl_down(vn, o, 64); vk += __shfl_down(vk, o, 64); }
  if (lane == 0) { sb[w] = vn; sb[8 + w] = vk; }
  __syncthreads();
  if (tid == 0) {
    float sn = 0.f, sk = 0.f;
#pragma unroll
    for (int i = 0; i < 8; ++i) { sn += sb[i]; sk += sb[8 + i]; }
    const float inv = 1.0f / (float)((size_t)Bdim * Tdim);
    float nll = 0.5f * (sn * inv + (float)DOUT * 1.8378770664093453f);
    float kl  = 0.5f * (sk * inv - (float)DZ);
    size_t o0 = (size_t)Bdim * Tdim * DOUT;
    gout[o0 + 0] = nll + kl;
    gout[o0 + 1] = nll;
    gout[o0 + 2] = kl;
  }
}

extern "C" void kernel_launch(void* const* d_in, const int* in_sizes, int n_in,
                              void* d_out, int out_size, void* d_ws, size_t ws_size,
                              hipStream_t stream) {
  (void)in_sizes; (void)n_in; (void)out_size; (void)ws_size;
  const float* gx  = (const float*)d_in[0];
  const float* gy  = (const float*)d_in[1];
  const float* pW1 = (const float*)d_in[2];  const float* pb1 = (const float*)d_in[3];
  const float* pW2 = (const float*)d_in[4];  const float* pb2 = (const float*)d_in[5];
  const float* pW3 = (const float*)d_in[6];  const float* pb3 = (const float*)d_in[7];
  const float* qW1 = (const float*)d_in[8];  const float* qb1 = (const float*)d_in[9];
  const float* qW2 = (const float*)d_in[10]; const float* qb2 = (const float*)d_in[11];
  const float* qW3 = (const float*)d_in[12]; const float* qb3 = (const float*)d_in[13];
  const float* eW1 = (const float*)d_in[14]; const float* eb1 = (const float*)d_in[15];
  const float* eW2 = (const float*)d_in[16]; const float* eb2 = (const float*)d_in[17];
  const float* eW3 = (const float*)d_in[18]; const float* eb3 = (const float*)d_in[19];
  const float* z0mu = (const float*)d_in[20];
  const float* z0lv = (const float*)d_in[21];
  float* gout = (float*)d_out;
  float* gws  = (float*)d_ws;

  unsigned ka0, ka1, kb0, kb1;
  tf2x32(0u, 42u, 0u, 0u, ka0, ka1);   // fold_in(key(42), 0) -> eps0 key
  tf2x32(0u, 42u, 0u, 1u, kb0, kb1);   // fold_in(key(42), 1) -> eps key

  dssm_main<<<NWG, NTHR, 0, stream>>>(gx, gy,
      pW1, pb1, pW2, pb2, pW3, pb3,
      qW1, qb1, qW2, qb2, qW3, qb3,
      eW1, eb1, eW2, eb2, eW3, eb3,
      z0mu, z0lv, gout, gws, ka0, ka1, kb0, kb1);
  dssm_fin<<<1, 512, 0, stream>>>(gws, gout);
}

// Round 6
// 2816.794 us; speedup vs baseline: 1.0169x; 1.0068x over previous
//
#include <hip/hip_runtime.h>
#include <stdint.h>

#define Bdim 1024
#define Tdim 512
#define DIN  64
#define DOUT 32
#define DZ   32
#define DH   128
#define Msamp 2
#define NWG  (Bdim / Msamp)   // 512 workgroups -> 2 blocks/CU
#define NTHR 512
#define SP   136              // padded row stride (bf16 elems)

using s16x8 = __attribute__((ext_vector_type(8))) short;   // 8 x bf16
using f32x4 = __attribute__((ext_vector_type(4))) float;

#define MFMA(a, b, c) __builtin_amdgcn_mfma_f32_16x16x32_bf16((a), (b), (c), 0, 0, 0)

// ---------------- threefry2x32 (JAX/Random123, 20 rounds) ----------------
__host__ __device__ inline void tf2x32(unsigned k0, unsigned k1, unsigned c0, unsigned c1,
                                       unsigned &o0, unsigned &o1) {
  unsigned ks2 = k0 ^ k1 ^ 0x1BD11BDAu;
  unsigned x0 = c0 + k0, x1 = c1 + k1;
#define TFR(r) { x0 += x1; x1 = (x1 << (r)) | (x1 >> (32 - (r))); x1 ^= x0; }
  TFR(13) TFR(15) TFR(26) TFR(6)
  x0 += k1;  x1 += ks2 + 1u;
  TFR(17) TFR(29) TFR(16) TFR(24)
  x0 += ks2; x1 += k0 + 2u;
  TFR(13) TFR(15) TFR(26) TFR(6)
  x0 += k0;  x1 += k1 + 3u;
  TFR(17) TFR(29) TFR(16) TFR(24)
  x0 += k1;  x1 += ks2 + 4u;
  TFR(13) TFR(15) TFR(26) TFR(6)
  x0 += ks2; x1 += k0 + 5u;
#undef TFR
  o0 = x0; o1 = x1;
}

__device__ inline float erfinv_xla(float x) {
  float w = -log1pf(-x * x);
  float p;
  if (w < 5.0f) {
    w -= 2.5f;
    p = 2.81022636e-08f;
    p = fmaf(p, w, 3.43273939e-07f);
    p = fmaf(p, w, -3.5233877e-06f);
    p = fmaf(p, w, -4.39150654e-06f);
    p = fmaf(p, w, 0.00021858087f);
    p = fmaf(p, w, -0.00125372503f);
    p = fmaf(p, w, -0.00417768164f);
    p = fmaf(p, w, 0.246640727f);
    p = fmaf(p, w, 1.50140941f);
  } else {
    w = sqrtf(w) - 3.0f;
    p = -0.000200214257f;
    p = fmaf(p, w, 0.000100950558f);
    p = fmaf(p, w, 0.00134934322f);
    p = fmaf(p, w, -0.00367342844f);
    p = fmaf(p, w, 0.00573950773f);
    p = fmaf(p, w, -0.0076224613f);
    p = fmaf(p, w, 0.00943887047f);
    p = fmaf(p, w, 1.00167406f);
    p = fmaf(p, w, 2.83297682f);
  }
  return p * x;
}

__device__ inline float bits_to_normal(unsigned bits) {
  float f = __uint_as_float((bits >> 9) | 0x3f800000u) - 1.0f;
  float u = f * 2.0f - 0.99999994f;
  u = fmaxf(u, -0.99999994f);
  return 1.41421356f * erfinv_xla(u);
}

// partitionable threefry: bits[i] = x0 ^ x1 of cipher(key, (0, i))
__device__ inline float jax_normal(unsigned k0, unsigned k1, unsigned idx) {
  unsigned o0, o1;
  tf2x32(k0, k1, 0u, idx, o0, o1);
  return bits_to_normal(o0 ^ o1);
}

// ---------------- small helpers ----------------
__device__ inline float clampf(float v) { return fminf(fmaxf(v, -10.0f), 2.0f); }
__device__ inline float tanh_fast(float v) {
  float e = __expf(2.0f * v);
  return 1.0f - __fdividef(2.0f, e + 1.0f);
}
__device__ inline short f2bf_rne(float x) {   // single v_cvt_pk_bf16_f32 (RNE)
  unsigned u;
  asm("v_cvt_pk_bf16_f32 %0, %1, %2" : "=v"(u) : "v"(x), "v"(x));
  return (short)(u & 0xffffu);
}

// one MFMA B-fragment (16 cols x 32 k) of fp32 W (K x N row-major) as bf16
__device__ inline s16x8 load_frag(const float* __restrict__ W, int N, int kt, int nt, int lane) {
  int k0 = kt * 32 + ((lane >> 4) << 3);
  int n  = nt * 16 + (lane & 15);
  s16x8 f;
#pragma unroll
  for (int e = 0; e < 8; ++e) {
    float x = W[(size_t)(k0 + e) * N + n];
    unsigned u = __float_as_uint(x);
    u = (u + 0x7fffu + ((u >> 16) & 1u)) >> 16;
    f[e] = (short)u;
  }
  return f;
}

// A-fragment pointer: rows 0..Msamp-1 real, rows >=Msamp -> shared zero page (broadcast)
__device__ inline const s16x8* afp(const short* buf, const short* zp, int lane) {
  int r = lane & 15;
  const short* p = (r < Msamp) ? (buf + r * SP) : zp;
  return (const s16x8*)(p + ((lane >> 4) << 3));
}

// spread 16x16 D-tile (valid rows 0..1, held by lanes 0-15 regs 0-1) across 32 lanes:
// lane l gets D[(l>>4)&1][l&15]; works identically for lanes 32-63.
__device__ __forceinline__ float spread2(int pi, f32x4 c, int lane) {
  int v0 = __builtin_amdgcn_ds_bpermute(pi, __float_as_int(c[0]));
  int v1 = __builtin_amdgcn_ds_bpermute(pi, __float_as_int(c[1]));
  return __int_as_float((lane & 16) ? v1 : v0);
}

// ---------------- main persistent kernel ----------------
__global__ __launch_bounds__(NTHR, 4) void dssm_main(
    const float* __restrict__ gx, const float* __restrict__ gy,
    const float* __restrict__ pW1, const float* __restrict__ pb1,
    const float* __restrict__ pW2, const float* __restrict__ pb2,
    const float* __restrict__ pW3, const float* __restrict__ pb3,
    const float* __restrict__ qW1, const float* __restrict__ qb1,
    const float* __restrict__ qW2, const float* __restrict__ qb2,
    const float* __restrict__ qW3, const float* __restrict__ qb3,
    const float* __restrict__ eW1, const float* __restrict__ eb1,
    const float* __restrict__ eW2, const float* __restrict__ eb2,
    const float* __restrict__ eW3, const float* __restrict__ eb3,
    const float* __restrict__ z0mu, const float* __restrict__ z0lv,
    float* __restrict__ gout, float* __restrict__ gws,
    unsigned ka0, unsigned ka1, unsigned kb0, unsigned kb1)
{
  // activations: 2 real rows per buffer; zero-page serves MFMA rows 2..15
  __shared__ __align__(16) short in_pq[2 * SP];                     // [z32|x64|y32]
  __shared__ __align__(16) short hpa[2 * SP], hqa[2 * SP], hea[2 * SP];
  __shared__ __align__(16) short hpb[2 * SP], hqb[2 * SP], heb[2 * SP];
  __shared__ __align__(16) short zpage[128];
  __shared__ __align__(16) s16x8 wlds[48 * 64];                     // 48 KiB weight frags
  __shared__ float out_p[2][64], out_q[2][64], emit_o[2][64];
  __shared__ float epsb[8][64];                                     // 8-step eps ring

  const int tid  = threadIdx.x;
  const int w    = tid >> 6;
  const int lane = tid & 63;
  const int wg   = blockIdx.x;
  const int base = wg * Msamp;
  const int col  = lane & 15;
  const int sRow = (lane >> 4) & 1;
  const int pi   = col << 2;                    // bpermute byte index (spread)
  const int pi32 = ((lane ^ 32) & 63) << 2;     // bpermute swap halves

  // ---- register weight fragments (same for all waves: 20 frags = 80 VGPR) ----
  s16x8 fP1[3], fQ1[4], fE1, fP2[4], fQ2[4], fT3[4];
#pragma unroll
  for (int kt = 0; kt < 3; ++kt) fP1[kt] = load_frag(pW1, DH, kt, w, lane);
#pragma unroll
  for (int kt = 0; kt < 4; ++kt) fQ1[kt] = load_frag(qW1, DH, kt, w, lane);
  fE1 = load_frag(eW1, DH, 0, w, lane);
#pragma unroll
  for (int kt = 0; kt < 4; ++kt) fP2[kt] = load_frag(pW2, DH, kt, w, lane);
#pragma unroll
  for (int kt = 0; kt < 4; ++kt) fQ2[kt] = load_frag(qW2, DH, kt, w, lane);
  {
    const float* W3 = (w < 4) ? eW3 : ((w < 6) ? qW3 : pW3);
    int nt3 = (w < 4) ? w : ((w < 6) ? (w - 4) : (w - 6));
#pragma unroll
    for (int kt = 0; kt < 4; ++kt) fT3[kt] = load_frag(W3, 2 * DOUT, kt, nt3, lane);
  }

  // ---- LDS weight fragments: emit W2 (32 frags) + lv-halves of q/p heads (8+8) ----
  for (int i = tid; i < 48 * 64; i += NTHR) {
    int fid = i >> 6, ln = i & 63;
    const float* W; int nt, kt = fid & 3;
    if (fid < 32)      { W = eW2; nt = fid >> 2;            wlds[i] = load_frag(W, DH, kt, nt, ln); }
    else if (fid < 40) { W = qW3; nt = 2 + ((fid - 32) >> 2); wlds[i] = load_frag(W, 64, kt, nt, ln); }
    else               { W = pW3; nt = 2 + ((fid - 40) >> 2); wlds[i] = load_frag(W, 64, kt, nt, ln); }
  }

  // ---- hoisted per-lane biases ----
  float b1  = (lane < 32) ? pb1[w * 16 + col] : qb1[w * 16 + col];
  float b1e = eb1[w * 16 + col];
  float b2  = (lane < 32) ? pb2[w * 16 + col] : qb2[w * 16 + col];
  float b2e = eb2[w * 16 + col];
  float b3;
  if (w < 4)      b3 = eb3[w * 16 + col];
  else if (w < 6) b3 = (lane < 32) ? qb3[(w - 4) * 16 + col] : qb3[32 + (w - 4) * 16 + col];
  else            b3 = (lane < 32) ? pb3[(w - 6) * 16 + col] : pb3[32 + (w - 6) * 16 + col];

  // ---- hoisted LDS pointers ----
  short* wp1  = ((lane < 32) ? hpa : hqa) + sRow * SP + w * 16 + col;
  short* wp1e = hea + sRow * SP + w * 16 + col;
  short* wp2  = ((lane < 32) ? hpb : hqb) + sRow * SP + w * 16 + col;
  short* wp2e = heb + sRow * SP + w * 16 + col;
  float* wp3;
  if (w < 4)      wp3 = &emit_o[sRow][w * 16 + col];
  else if (w < 6) wp3 = &out_q[sRow][((lane >= 32) ? 32 : 0) + (w - 4) * 16 + col];
  else            wp3 = &out_p[sRow][((lane >= 32) ? 32 : 0) + (w - 6) * 16 + col];
  short* zwp = &in_pq[sRow * SP + ((w - 4) & 3) * 16 + col];
  const int epsi = sRow * 32 + ((w - 4) & 3) * 16 + col;

  const s16x8* aIn = afp(in_pq, zpage, lane);
  const s16x8* aPa = afp(hpa, zpage, lane);
  const s16x8* aQa = afp(hqa, zpage, lane);
  const s16x8* aEa = afp(hea, zpage, lane);
  const s16x8* aPb = afp(hpb, zpage, lane);
  const s16x8* aQb = afp(hqb, zpage, lane);
  const s16x8* aEb = afp(heb, zpage, lane);
  const s16x8* aH  = (w < 6) ? aQb : aPb;
  const s16x8* wE2 = &wlds[lane] + (w * 4) * 64;                       // emit W2 frags
  const s16x8* wH3 = &wlds[lane] + (((w < 6) ? 32 + ((w - 4) & 3) * 4 : 40 + (w - 6) * 4)) * 64;

  // ---- prologue: zero page, t=0 inputs, z0 ----
  if (tid < 128) zpage[tid] = 0;
  float yq0 = 0.f, yq1 = 0.f, yq2 = 0.f, xv = 0.f, yv = 0.f;
  if (tid < 128) {
    int s = tid >> 6, j = tid & 63;
    in_pq[s * SP + 32 + j] = f2bf_rne(gx[((size_t)(base + s) * Tdim) * DIN + j]);
  }
  if (w == 1) {
    int s = lane >> 5, j = lane & 31;
    yq2 = gy[((size_t)(base + s) * Tdim) * DOUT + j];
    in_pq[s * SP + 96 + j] = f2bf_rne(yq2);
  }
  if (tid < 64) {
    int s = tid >> 5, zd = tid & 31;
    float e0 = jax_normal(ka0, ka1, (unsigned)(base + s) * DZ + zd);
    float lv = clampf(z0lv[zd]);
    in_pq[s * SP + zd] = f2bf_rne(z0mu[zd] + __expf(0.5f * lv) * e0);
  }
  __syncthreads();

  float kl_acc = 0.f, nll_acc = 0.f;

#pragma unroll 1
  for (int t = 0; t <= Tdim; ++t) {
    // ======== PHASE 1: L1 (prior+post+emit) | eps batch | prefetch | KL(t-1) ========
    if ((t & 7) == 0 && t < Tdim) {
      unsigned idx = (unsigned)(t + w) * (unsigned)(Bdim * DZ)
                   + (unsigned)(base + (lane >> 5)) * DZ + (lane & 31);
      epsb[w][lane] = jax_normal(kb0, kb1, idx);
    }
    if (t + 1 < Tdim) {
      if (w == 2 || w == 3) xv = gx[((size_t)(base + (w - 2)) * Tdim + (t + 1)) * DIN + lane];
      if (w == 1)           yv = gy[((size_t)(base + (lane >> 5)) * Tdim + (t + 1)) * DOUT + (lane & 31)];
    }
    f32x4 cP = {0.f, 0.f, 0.f, 0.f}, cQ = {0.f, 0.f, 0.f, 0.f}, cE = {0.f, 0.f, 0.f, 0.f};
    cP = MFMA(aIn[0], fP1[0], cP); cP = MFMA(aIn[4], fP1[1], cP); cP = MFMA(aIn[8], fP1[2], cP);
    cQ = MFMA(aIn[0], fQ1[0], cQ); cQ = MFMA(aIn[4], fQ1[1], cQ);
    cQ = MFMA(aIn[8], fQ1[2], cQ); cQ = MFMA(aIn[12], fQ1[3], cQ);
    cE = MFMA(aIn[0], fE1, cE);
    if (w == 0 && t >= 1) {
      int s = lane >> 5, zd = lane & 31;
      float mq = out_q[s][zd], lq = clampf(out_q[s][32 + zd]);
      float mp = out_p[s][zd], lp = clampf(out_p[s][32 + zd]);
      float dm = mq - mp;
      kl_acc += lp - lq + (__expf(lq) + dm * dm) / (__expf(lp) + 1e-12f);
    }
    {
      float vP = spread2(pi, cP, lane), vQ = spread2(pi, cQ, lane);
      float vE = spread2(pi, cE, lane);
      float v  = (lane >= 32) ? vQ : vP;
      *wp1 = f2bf_rne(tanh_fast(v + b1));
      if (lane < 32) *wp1e = f2bf_rne(tanh_fast(vE + b1e));
    }
    __syncthreads();

    // ======== PHASE 2: L2 (prior+post+emit[LDS frags]) | NLL(t-2) ========
    f32x4 dP = {0.f, 0.f, 0.f, 0.f}, dQ = {0.f, 0.f, 0.f, 0.f}, dE = {0.f, 0.f, 0.f, 0.f};
#pragma unroll
    for (int kt = 0; kt < 4; ++kt) {
      dP = MFMA(aPa[kt * 4], fP2[kt], dP);
      dQ = MFMA(aQa[kt * 4], fQ2[kt], dQ);
      dE = MFMA(aEa[kt * 4], wE2[kt * 64], dE);
    }
    if (w == 1 && t >= 2) {
      int s = lane >> 5, j = lane & 31;
      float mu = emit_o[s][j], lv = clampf(emit_o[s][32 + j]);
      float d = yq0 - mu;
      nll_acc += lv + d * d * __expf(-lv);
    }
    {
      float vP = spread2(pi, dP, lane), vQ = spread2(pi, dQ, lane);
      float vE = spread2(pi, dE, lane);
      float v  = (lane >= 32) ? vQ : vP;
      *wp2 = f2bf_rne(tanh_fast(v + b2));
      if (lane < 32) *wp2e = f2bf_rne(tanh_fast(vE + b2e));
    }
    __syncthreads();

    // ======== PHASE 3: heads + emit L3 + in-reg z-sample + x/y commit ========
    if (w < 4) {
      f32x4 e = {0.f, 0.f, 0.f, 0.f};
#pragma unroll
      for (int kt = 0; kt < 4; ++kt) e = MFMA(aEb[kt * 4], fT3[kt], e);
      float v = spread2(pi, e, lane) + b3;
      if (lane < 32) {
        *wp3 = v;
        if (w < 2 && t >= 1)
          gout[((size_t)(base + sRow) * Tdim + (t - 1)) * DOUT + w * 16 + col] = v;
      }
    } else {
      f32x4 cM = {0.f, 0.f, 0.f, 0.f}, cL = {0.f, 0.f, 0.f, 0.f};
#pragma unroll
      for (int kt = 0; kt < 4; ++kt) {
        cM = MFMA(aH[kt * 4], fT3[kt], cM);
        cL = MFMA(aH[kt * 4], wH3[kt * 64], cL);
      }
      float vM = spread2(pi, cM, lane), vL = spread2(pi, cL, lane);
      float v  = ((lane >= 32) ? vL : vM) + b3;
      *wp3 = v;
      // q-head waves sample z_t in-register (lv pulled from sibling half-wave)
      float vswap = __int_as_float(__builtin_amdgcn_ds_bpermute(pi32, __float_as_int(v)));
      if (w < 6 && lane < 32) {
        float lvq = clampf(vswap);
        float z = v + __expf(0.5f * lvq) * epsb[t & 7][epsi];
        *zwp = f2bf_rne(z);
      }
    }
    if (t + 1 < Tdim) {
      if (w == 2 || w == 3) in_pq[(w - 2) * SP + 32 + lane] = f2bf_rne(xv);
      if (w == 1)           in_pq[(lane >> 5) * SP + 96 + (lane & 31)] = f2bf_rne(yv);
    }
    if (w == 1) { yq0 = yq1; yq1 = yq2; yq2 = yv; }
    __syncthreads();
  }

  // final NLL (step 511; emit_o from last iteration, visible after loop barrier)
  if (w == 1) {
    int s = lane >> 5, j = lane & 31;
    float mu = emit_o[s][j], lv = clampf(emit_o[s][32 + j]);
    float d = yq0 - mu;
    nll_acc += lv + d * d * __expf(-lv);
  }

  // per-WG reduction: wave1 holds nll, wave0 holds kl
  float vn = nll_acc, vk = kl_acc;
#pragma unroll
  for (int o = 32; o > 0; o >>= 1) { vn += __shfl_down(vn, o, 64); vk += __shfl_down(vk, o, 64); }
  if (tid == 64) gws[wg] = vn;
  if (tid == 0)  gws[NWG + wg] = vk;
}

// ---------------- finalize ----------------
__global__ void dssm_fin(const float* __restrict__ gws, float* __restrict__ gout) {
  __shared__ float sb[16];
  int tid = threadIdx.x;   // 512
  int w = tid >> 6, lane = tid & 63;
  float vn = gws[tid], vk = gws[NWG + tid];
#pragma unroll
  for (int o = 32; o > 0; o >>= 1) { vn += __shfl_down(vn, o, 64); vk += __shfl_down(vk, o, 64); }
  if (lane == 0) { sb[w] = vn; sb[8 + w] = vk; }
  __syncthreads();
  if (tid == 0) {
    float sn = 0.f, sk = 0.f;
#pragma unroll
    for (int i = 0; i < 8; ++i) { sn += sb[i]; sk += sb[8 + i]; }
    const float inv = 1.0f / (float)((size_t)Bdim * Tdim);
    float nll = 0.5f * (sn * inv + (float)DOUT * 1.8378770664093453f);
    float kl  = 0.5f * (sk * inv - (float)DZ);
    size_t o0 = (size_t)Bdim * Tdim * DOUT;
    gout[o0 + 0] = nll + kl;
    gout[o0 + 1] = nll;
    gout[o0 + 2] = kl;
  }
}

extern "C" void kernel_launch(void* const* d_in, const int* in_sizes, int n_in,
                              void* d_out, int out_size, void* d_ws, size_t ws_size,
                              hipStream_t stream) {
  (void)in_sizes; (void)n_in; (void)out_size; (void)ws_size;
  const float* gx  = (const float*)d_in[0];
  const float* gy  = (const float*)d_in[1];
  const float* pW1 = (const float*)d_in[2];  const float* pb1 = (const float*)d_in[3];
  const float* pW2 = (const float*)d_in[4];  const float* pb2 = (const float*)d_in[5];
  const float* pW3 = (const float*)d_in[6];  const float* pb3 = (const float*)d_in[7];
  const float* qW1 = (const float*)d_in[8];  const float* qb1 = (const float*)d_in[9];
  const float* qW2 = (const float*)d_in[10]; const float* qb2 = (const float*)d_in[11];
  const float* qW3 = (const float*)d_in[12]; const float* qb3 = (const float*)d_in[13];
  const float* eW1 = (const float*)d_in[14]; const float* eb1 = (const float*)d_in[15];
  const float* eW2 = (const float*)d_in[16]; const float* eb2 = (const float*)d_in[17];
  const float* eW3 = (const float*)d_in[18]; const float* eb3 = (const float*)d_in[19];
  const float* z0mu = (const float*)d_in[20];
  const float* z0lv = (const float*)d_in[21];
  float* gout = (float*)d_out;
  float* gws  = (float*)d_ws;

  unsigned ka0, ka1, kb0, kb1;
  tf2x32(0u, 42u, 0u, 0u, ka0, ka1);   // fold_in(key(42), 0) -> eps0 key
  tf2x32(0u, 42u, 0u, 1u, kb0, kb1);   // fold_in(key(42), 1) -> eps key

  dssm_main<<<NWG, NTHR, 0, stream>>>(gx, gy,
      pW1, pb1, pW2, pb2, pW3, pb3,
      qW1, qb1, qW2, qb2, qW3, qb3,
      eW1, eb1, eW2, eb2, eW3, eb3,
      z0mu, z0lv, gout, gws, ka0, ka1, kb0, kb1);
  dssm_fin<<<1, 512, 0, stream>>>(gws, gout);
}

// Round 7
// 887.738 us; speedup vs baseline: 3.2268x; 3.1730x over previous
//
#include <hip/hip_runtime.h>
#include <stdint.h>

#define Bdim 1024
#define Tdim 512
#define DIN  64
#define DOUT 32
#define DZ   32
#define DH   128
#define Msamp 4
#define NWG  256          // Bdim / Msamp -> 1 block/CU
#define NTHR 512
#define SP   144          // bf16 row stride: 288B -> bank-uniform dup-row A-reads

using s16x8 = __attribute__((ext_vector_type(8))) short;   // 8 x bf16
using f32x4 = __attribute__((ext_vector_type(4))) float;

#define MFMA(a, b, c) __builtin_amdgcn_mfma_f32_16x16x32_bf16((a), (b), (c), 0, 0, 0)

// Raw barrier: LDS visibility (lgkmcnt) only — does NOT drain vmcnt, so global
// prefetch loads issued in P1 stay in flight until their P3 use.
#define BAR() do { asm volatile("s_waitcnt lgkmcnt(0)" ::: "memory"); \
                   __builtin_amdgcn_s_barrier();                      \
                   asm volatile("" ::: "memory"); } while (0)

// ---------------- threefry2x32 (JAX/Random123, 20 rounds) ----------------
__host__ __device__ inline void tf2x32(unsigned k0, unsigned k1, unsigned c0, unsigned c1,
                                       unsigned &o0, unsigned &o1) {
  unsigned ks2 = k0 ^ k1 ^ 0x1BD11BDAu;
  unsigned x0 = c0 + k0, x1 = c1 + k1;
#define TFR(r) { x0 += x1; x1 = (x1 << (r)) | (x1 >> (32 - (r))); x1 ^= x0; }
  TFR(13) TFR(15) TFR(26) TFR(6)
  x0 += k1;  x1 += ks2 + 1u;
  TFR(17) TFR(29) TFR(16) TFR(24)
  x0 += ks2; x1 += k0 + 2u;
  TFR(13) TFR(15) TFR(26) TFR(6)
  x0 += k0;  x1 += k1 + 3u;
  TFR(17) TFR(29) TFR(16) TFR(24)
  x0 += k1;  x1 += ks2 + 4u;
  TFR(13) TFR(15) TFR(26) TFR(6)
  x0 += ks2; x1 += k0 + 5u;
#undef TFR
  o0 = x0; o1 = x1;
}

__device__ inline float erfinv_xla(float x) {
  float w = -log1pf(-x * x);
  float p;
  if (w < 5.0f) {
    w -= 2.5f;
    p = 2.81022636e-08f;
    p = fmaf(p, w, 3.43273939e-07f);
    p = fmaf(p, w, -3.5233877e-06f);
    p = fmaf(p, w, -4.39150654e-06f);
    p = fmaf(p, w, 0.00021858087f);
    p = fmaf(p, w, -0.00125372503f);
    p = fmaf(p, w, -0.00417768164f);
    p = fmaf(p, w, 0.246640727f);
    p = fmaf(p, w, 1.50140941f);
  } else {
    w = sqrtf(w) - 3.0f;
    p = -0.000200214257f;
    p = fmaf(p, w, 0.000100950558f);
    p = fmaf(p, w, 0.00134934322f);
    p = fmaf(p, w, -0.00367342844f);
    p = fmaf(p, w, 0.00573950773f);
    p = fmaf(p, w, -0.0076224613f);
    p = fmaf(p, w, 0.00943887047f);
    p = fmaf(p, w, 1.00167406f);
    p = fmaf(p, w, 2.83297682f);
  }
  return p * x;
}

__device__ inline float bits_to_normal(unsigned bits) {
  float f = __uint_as_float((bits >> 9) | 0x3f800000u) - 1.0f;
  float u = f * 2.0f - 0.99999994f;
  u = fmaxf(u, -0.99999994f);
  return 1.41421356f * erfinv_xla(u);
}

// partitionable threefry: bits[i] = x0 ^ x1 of cipher(key, (0, i))
__device__ inline float jax_normal(unsigned k0, unsigned k1, unsigned idx) {
  unsigned o0, o1;
  tf2x32(k0, k1, 0u, idx, o0, o1);
  return bits_to_normal(o0 ^ o1);
}

// ---------------- helpers ----------------
__device__ inline float clampf(float v) { return fminf(fmaxf(v, -10.0f), 2.0f); }
__device__ inline float tanh_fast(float v) {
  float e = __expf(2.0f * v);
  return 1.0f - __fdividef(2.0f, e + 1.0f);
}
__device__ inline short f2bf(float x) {  // RNE float->bf16
  unsigned u = __float_as_uint(x);
  u = (u + 0x7fffu + ((u >> 16) & 1u)) >> 16;
  return (short)u;
}
// With dup-row A-fragments, every lane's c[r] == row r content; pick row g.
__device__ inline float sel4(f32x4 v, int g) {
  float r = v[0];
  r = (g == 1) ? v[1] : r;
  r = (g == 2) ? v[2] : r;
  r = (g == 3) ? v[3] : r;
  return r;
}

// one MFMA B-fragment (16 cols x 32 k) of fp32 W (K x N row-major) as bf16
__device__ inline s16x8 load_frag(const float* __restrict__ W, int N, int kt, int nt, int lane) {
  int k0 = kt * 32 + ((lane >> 4) << 3);
  int n  = nt * 16 + (lane & 15);
  s16x8 f;
#pragma unroll
  for (int e = 0; e < 8; ++e) f[e] = f2bf(W[(size_t)(k0 + e) * N + n]);
  return f;
}

// ---------------- main persistent kernel ----------------
__global__ __launch_bounds__(NTHR, 2) void dssm_main(
    const float* __restrict__ gx, const float* __restrict__ gy,
    const float* __restrict__ pW1, const float* __restrict__ pb1,
    const float* __restrict__ pW2, const float* __restrict__ pb2,
    const float* __restrict__ pW3, const float* __restrict__ pb3,
    const float* __restrict__ qW1, const float* __restrict__ qb1,
    const float* __restrict__ qW2, const float* __restrict__ qb2,
    const float* __restrict__ qW3, const float* __restrict__ qb3,
    const float* __restrict__ eW1, const float* __restrict__ eb1,
    const float* __restrict__ eW2, const float* __restrict__ eb2,
    const float* __restrict__ eW3, const float* __restrict__ eb3,
    const float* __restrict__ z0mu, const float* __restrict__ z0lv,
    float* __restrict__ gout, float* __restrict__ gws,
    unsigned ka0, unsigned ka1, unsigned kb0, unsigned kb1)
{
  __shared__ __align__(16) short in_pq[4 * SP];                 // [z32|x64|y32]
  __shared__ __align__(16) short hpa[4 * SP], hqa[4 * SP], hea[4 * SP];
  __shared__ __align__(16) short hpb[4 * SP], hqb[4 * SP], heb[4 * SP];
  __shared__ float out_q2[4][32][2], out_p2[4][32][2], emit_o2[4][32][2];
  __shared__ float y_f32[4][128];   // 4-deep y ring (fp32 exact)
  __shared__ float epsb[2][128];    // eps(t) at slot t&1

  const int tid  = threadIdx.x;
  const int w    = tid >> 6;
  const int lane = tid & 63;
  const int col  = lane & 15;
  const int g    = lane >> 4;       // 0..3
  const int wg   = blockIdx.x;
  const int base = wg * Msamp;

  // ---- register weight fragments ----
  s16x8 f1p[3], f1q[4], f1e, f2[16], f3[8];
#pragma unroll
  for (int i = 0; i < 16; ++i) f2[i] = (s16x8)(short)0;
#pragma unroll
  for (int i = 0; i < 8; ++i) f3[i] = (s16x8)(short)0;

#pragma unroll
  for (int kt = 0; kt < 3; ++kt) f1p[kt] = load_frag(pW1, DH, kt, w, lane);
#pragma unroll
  for (int kt = 0; kt < 4; ++kt) f1q[kt] = load_frag(qW1, DH, kt, w, lane);
  f1e = load_frag(eW1, DH, 0, w, lane);

  if (w < 2) {
#pragma unroll
    for (int nt = 0; nt < 4; ++nt)
#pragma unroll
      for (int kt = 0; kt < 4; ++kt) f2[nt * 4 + kt] = load_frag(pW2, DH, kt, w * 4 + nt, lane);
  } else if (w < 4) {
#pragma unroll
    for (int nt = 0; nt < 4; ++nt)
#pragma unroll
      for (int kt = 0; kt < 4; ++kt) f2[nt * 4 + kt] = load_frag(qW2, DH, kt, (w - 2) * 4 + nt, lane);
  } else if (w < 6) {
#pragma unroll
    for (int nt = 0; nt < 4; ++nt)
#pragma unroll
      for (int kt = 0; kt < 4; ++kt) f2[nt * 4 + kt] = load_frag(eW2, DH, kt, (w - 4) * 4 + nt, lane);
  }

  if (w < 4) {
#pragma unroll
    for (int kt = 0; kt < 4; ++kt) f3[kt] = load_frag(eW3, 2 * DOUT, kt, w, lane);
  } else if (w < 6) {
#pragma unroll
    for (int kt = 0; kt < 4; ++kt) { f3[kt] = load_frag(qW3, 2 * DZ, kt, w - 4, lane);
                                     f3[4 + kt] = load_frag(qW3, 2 * DZ, kt, w - 2, lane); }
  } else {
#pragma unroll
    for (int kt = 0; kt < 4; ++kt) { f3[kt] = load_frag(pW3, 2 * DZ, kt, w - 6, lane);
                                     f3[4 + kt] = load_frag(pW3, 2 * DZ, kt, w - 4, lane); }
  }

  // ---- biases (per-lane) ----
  const float b1p = pb1[w * 16 + col], b1q = qb1[w * 16 + col], b1e = eb1[w * 16 + col];
  float b2[4];
#pragma unroll
  for (int nt = 0; nt < 4; ++nt) {
    int n = ((w & 1) * 4 + nt) * 16 + col;
    b2[nt] = (w < 2) ? pb2[n] : (w < 4) ? qb2[n] : (w < 6) ? eb2[n] : 0.0f;
  }
  float b3a = 0.0f, b3b = 0.0f;
  if (w < 4)      { b3a = eb3[w * 16 + col]; }
  else if (w < 6) { b3a = qb3[(w - 4) * 16 + col]; b3b = qb3[32 + (w - 4) * 16 + col]; }
  else            { b3a = pb3[(w - 6) * 16 + col]; b3b = pb3[32 + (w - 6) * 16 + col]; }

  // ---- hoisted A-fragment pointers (dup-row: row = col&3) ----
  const s16x8* A1 = (const s16x8*)(in_pq + (col & 3) * SP) + g;
  const short* p2s = (w < 2) ? hpa : (w < 4) ? hqa : hea;
  const s16x8* A2 = (const s16x8*)(p2s + (col & 3) * SP) + g;
  short* p2d = (w < 2) ? hpb : (w < 4) ? hqb : heb;
  const short* p3s = (w < 4) ? heb : (w < 6) ? hqb : hpb;
  const s16x8* A3 = (const s16x8*)(p3s + (col & 3) * SP) + g;

  // ---- prologue: t=0 inputs, z0, eps(0) ----
  if (w < 4) {
    in_pq[w * SP + 32 + lane] = f2bf(gx[((size_t)(base + w) * Tdim) * DIN + lane]);
  } else if (w < 6) {
    int s = (w - 4) * 2 + (lane >> 5), j = lane & 31;
    float yv = gy[((size_t)(base + s) * Tdim) * DOUT + j];
    in_pq[s * SP + 96 + j] = f2bf(yv);
    y_f32[0][s * 32 + j] = yv;
  } else {
    int s = (w - 6) * 2 + (lane >> 5), zd = lane & 31;
    float e0 = jax_normal(ka0, ka1, (unsigned)(base + s) * 32u + (unsigned)zd);
    float lv = clampf(z0lv[zd]);
    in_pq[s * SP + zd] = f2bf(z0mu[zd] + __expf(0.5f * lv) * e0);
  }
  if (w == 0) epsb[0][lane] = jax_normal(kb0, kb1, (unsigned)base * 32u + lane);
  if (w == 1) epsb[0][64 + lane] = jax_normal(kb0, kb1, (unsigned)base * 32u + 64u + lane);
  BAR();

  float kl_acc = 0.0f, nll_acc = 0.0f;
  float xnext = 0.0f, ynext = 0.0f;

#pragma unroll 1
  for (int t = 0; t <= Tdim; ++t) {
    // ================= PHASE 1: L1 (prior/post/emit) + prefetch =================
    if (w < 4 && t < Tdim - 1)
      xnext = gx[((size_t)(base + w) * Tdim + (t + 1)) * DIN + lane];
    if ((w == 4 || w == 5) && t < Tdim - 1)
      ynext = gy[((size_t)(base + (w - 4) * 2 + (lane >> 5)) * Tdim + (t + 1)) * DOUT + (lane & 31)];

    {
      s16x8 a0 = A1[0], a1 = A1[4], a2 = A1[8], a3 = A1[12];
      f32x4 cE = {0.f, 0.f, 0.f, 0.f};
      cE = MFMA(a0, f1e, cE);                       // emit L1 uses z (= z_{t-1})
      hea[g * SP + w * 16 + col] = f2bf(tanh_fast(sel4(cE, g) + b1e));
      if (t < Tdim) {
        f32x4 cP = {0.f, 0.f, 0.f, 0.f}, cQ = {0.f, 0.f, 0.f, 0.f};
        cP = MFMA(a0, f1p[0], cP); cP = MFMA(a1, f1p[1], cP); cP = MFMA(a2, f1p[2], cP);
        cQ = MFMA(a0, f1q[0], cQ); cQ = MFMA(a1, f1q[1], cQ);
        cQ = MFMA(a2, f1q[2], cQ); cQ = MFMA(a3, f1q[3], cQ);
        hpa[g * SP + w * 16 + col] = f2bf(tanh_fast(sel4(cP, g) + b1p));
        hqa[g * SP + w * 16 + col] = f2bf(tanh_fast(sel4(cQ, g) + b1q));
      }
    }
    BAR();

    // ================= PHASE 2: L2 slices | KL(t-1) | NLL(t-2) =================
    if (w < 6) {
      if (w >= 4 || t < Tdim) {   // emit-L2 always; p/q-L2 only while stepping
        s16x8 a0 = A2[0], a1 = A2[4], a2 = A2[8], a3 = A2[12];
        f32x4 d0 = {0.f,0.f,0.f,0.f}, d1 = {0.f,0.f,0.f,0.f},
              d2 = {0.f,0.f,0.f,0.f}, d3 = {0.f,0.f,0.f,0.f};
        d0 = MFMA(a0, f2[0],  d0); d0 = MFMA(a1, f2[1],  d0);
        d0 = MFMA(a2, f2[2],  d0); d0 = MFMA(a3, f2[3],  d0);
        d1 = MFMA(a0, f2[4],  d1); d1 = MFMA(a1, f2[5],  d1);
        d1 = MFMA(a2, f2[6],  d1); d1 = MFMA(a3, f2[7],  d1);
        d2 = MFMA(a0, f2[8],  d2); d2 = MFMA(a1, f2[9],  d2);
        d2 = MFMA(a2, f2[10], d2); d2 = MFMA(a3, f2[11], d2);
        d3 = MFMA(a0, f2[12], d3); d3 = MFMA(a1, f2[13], d3);
        d3 = MFMA(a2, f2[14], d3); d3 = MFMA(a3, f2[15], d3);
        int nb = (w & 1) * 4;
        p2d[g * SP + (nb + 0) * 16 + col] = f2bf(tanh_fast(sel4(d0, g) + b2[0]));
        p2d[g * SP + (nb + 1) * 16 + col] = f2bf(tanh_fast(sel4(d1, g) + b2[1]));
        p2d[g * SP + (nb + 2) * 16 + col] = f2bf(tanh_fast(sel4(d2, g) + b2[2]));
        p2d[g * SP + (nb + 3) * 16 + col] = f2bf(tanh_fast(sel4(d3, g) + b2[3]));
      }
    } else if (w == 6) {
      if (t >= 1) {
        float2 q0 = *(const float2*)&out_q2[g][col][0];
        float2 p0 = *(const float2*)&out_p2[g][col][0];
        float2 q1 = *(const float2*)&out_q2[g][col + 16][0];
        float2 p1 = *(const float2*)&out_p2[g][col + 16][0];
        float dm0 = q0.x - p0.x, dm1 = q1.x - p1.x;
        kl_acc += p0.y - q0.y + (__expf(q0.y) + dm0 * dm0) / (__expf(p0.y) + 1e-12f);
        kl_acc += p1.y - q1.y + (__expf(q1.y) + dm1 * dm1) / (__expf(p1.y) + 1e-12f);
      }
    } else {
      if (t >= 2) {
        float2 e0 = *(const float2*)&emit_o2[g][col][0];
        float2 e1 = *(const float2*)&emit_o2[g][col + 16][0];
        float y0 = y_f32[(t - 2) & 3][g * 32 + col];
        float y1 = y_f32[(t - 2) & 3][g * 32 + col + 16];
        float d0 = y0 - e0.x, d1 = y1 - e1.x;
        nll_acc += e0.y + d0 * d0 * __expf(-e0.y);
        nll_acc += e1.y + d1 * d1 * __expf(-e1.y);
      }
    }
    BAR();

    // ========= PHASE 3: heads + emit-L3 + z-sample + commits + eps(t+1) =========
    if (w < 4) {
      // emit L3, n-tile w (always; output is for step t-1)
      s16x8 a0 = A3[0], a1 = A3[4], a2 = A3[8], a3 = A3[12];
      f32x4 e = {0.f, 0.f, 0.f, 0.f};
      e = MFMA(a0, f3[0], e); e = MFMA(a1, f3[1], e);
      e = MFMA(a2, f3[2], e); e = MFMA(a3, f3[3], e);
      float v = sel4(e, g) + b3a;
      if (w < 2) {   // mu_y cols w*16..
        if (t >= 1)
          gout[((size_t)(base + g) * Tdim + (t - 1)) * DOUT + w * 16 + col] = v;
        emit_o2[g][w * 16 + col][0] = v;
      } else {       // lv_y cols (w-2)*16..  (store clamped for NLL)
        emit_o2[g][(w - 2) * 16 + col][1] = clampf(v);
        if (t < Tdim - 1)   // eps(t+1) on w2/w3
          epsb[(t + 1) & 1][(w - 2) * 64 + lane] =
              jax_normal(kb0, kb1, (unsigned)(t + 1) * 32768u + (unsigned)base * 32u + (w - 2) * 64u + lane);
      }
      if (t < Tdim - 1) in_pq[w * SP + 32 + lane] = f2bf(xnext);   // commit x(t+1)
    } else if (t < Tdim) {
      // q/p heads: two n-tiles {w-4 or w-6, +2} -> mu & lv for 16 cols
      s16x8 a0 = A3[0], a1 = A3[4], a2 = A3[8], a3 = A3[12];
      f32x4 cM = {0.f,0.f,0.f,0.f}, cL = {0.f,0.f,0.f,0.f};
      cM = MFMA(a0, f3[0], cM); cM = MFMA(a1, f3[1], cM);
      cM = MFMA(a2, f3[2], cM); cM = MFMA(a3, f3[3], cM);
      cL = MFMA(a0, f3[4], cL); cL = MFMA(a1, f3[5], cL);
      cL = MFMA(a2, f3[6], cL); cL = MFMA(a3, f3[7], cL);
      float mu = sel4(cM, g) + b3a;
      float lv = clampf(sel4(cL, g) + b3b);
      int jc = (w & 1) * 16 + col;
      if (w < 6) {
        float z = mu + __expf(0.5f * lv) * epsb[t & 1][g * 32 + jc];
        in_pq[g * SP + jc] = f2bf(z);                       // z_t for next iter
        *(float2*)&out_q2[g][jc][0] = make_float2(mu, lv);
        if (t < Tdim - 1) {                                  // commit y(t+1)
          int s = (w - 4) * 2 + (lane >> 5), j = lane & 31;
          in_pq[s * SP + 96 + j] = f2bf(ynext);
          y_f32[(t + 1) & 3][s * 32 + j] = ynext;
        }
      } else {
        *(float2*)&out_p2[g][jc][0] = make_float2(mu, lv);
      }
    }
    BAR();
  }

  // final NLL(T-1): emit_o2 from flush iter, y_f32 slot (T-1)&3
  if (w == 7) {
    float2 e0 = *(const float2*)&emit_o2[g][col][0];
    float2 e1 = *(const float2*)&emit_o2[g][col + 16][0];
    float y0 = y_f32[(Tdim - 1) & 3][g * 32 + col];
    float y1 = y_f32[(Tdim - 1) & 3][g * 32 + col + 16];
    float d0 = y0 - e0.x, d1 = y1 - e1.x;
    nll_acc += e0.y + d0 * d0 * __expf(-e0.y);
    nll_acc += e1.y + d1 * d1 * __expf(-e1.y);
  }

  // per-WG reduction: w7 holds nll, w6 holds kl
  float vn = nll_acc, vk = kl_acc;
#pragma unroll
  for (int o = 32; o > 0; o >>= 1) { vn += __shfl_down(vn, o, 64); vk += __shfl_down(vk, o, 64); }
  if (w == 7 && lane == 0) gws[wg] = vn;
  if (w == 6 && lane == 0) gws[NWG + wg] = vk;
}

// ---------------- finalize: reduce 256 partials ----------------
__global__ void dssm_fin(const float* __restrict__ gws, float* __restrict__ gout) {
  __shared__ float sb[8];
  int tid = threadIdx.x;   // 256
  int w = tid >> 6, lane = tid & 63;
  float vn = gws[tid], vk = gws[NWG + tid];
#pragma unroll
  for (int o = 32; o > 0; o >>= 1) { vn += __shfl_down(vn, o, 64); vk += __shfl_down(vk, o, 64); }
  if (lane == 0) { sb[w] = vn; sb[4 + w] = vk; }
  __syncthreads();
  if (tid == 0) {
    float sn = 0.f, sk = 0.f;
#pragma unroll
    for (int i = 0; i < 4; ++i) { sn += sb[i]; sk += sb[4 + i]; }
    const float inv = 1.0f / (float)((size_t)Bdim * Tdim);
    float nll = 0.5f * (sn * inv + (float)DOUT * 1.8378770664093453f);
    float kl  = 0.5f * (sk * inv - (float)DZ);
    size_t o0 = (size_t)Bdim * Tdim * DOUT;
    gout[o0 + 0] = nll + kl;
    gout[o0 + 1] = nll;
    gout[o0 + 2] = kl;
  }
}

extern "C" void kernel_launch(void* const* d_in, const int* in_sizes, int n_in,
                              void* d_out, int out_size, void* d_ws, size_t ws_size,
                              hipStream_t stream) {
  (void)in_sizes; (void)n_in; (void)out_size; (void)ws_size;
  const float* gx  = (const float*)d_in[0];
  const float* gy  = (const float*)d_in[1];
  const float* pW1 = (const float*)d_in[2];  const float* pb1 = (const float*)d_in[3];
  const float* pW2 = (const float*)d_in[4];  const float* pb2 = (const float*)d_in[5];
  const float* pW3 = (const float*)d_in[6];  const float* pb3 = (const float*)d_in[7];
  const float* qW1 = (const float*)d_in[8];  const float* qb1 = (const float*)d_in[9];
  const float* qW2 = (const float*)d_in[10]; const float* qb2 = (const float*)d_in[11];
  const float* qW3 = (const float*)d_in[12]; const float* qb3 = (const float*)d_in[13];
  const float* eW1 = (const float*)d_in[14]; const float* eb1 = (const float*)d_in[15];
  const float* eW2 = (const float*)d_in[16]; const float* eb2 = (const float*)d_in[17];
  const float* eW3 = (const float*)d_in[18]; const float* eb3 = (const float*)d_in[19];
  const float* z0mu = (const float*)d_in[20];
  const float* z0lv = (const float*)d_in[21];
  float* gout = (float*)d_out;
  float* gws  = (float*)d_ws;

  unsigned ka0, ka1, kb0, kb1;
  tf2x32(0u, 42u, 0u, 0u, ka0, ka1);   // fold_in(key(42), 0) -> eps0 key
  tf2x32(0u, 42u, 0u, 1u, kb0, kb1);   // fold_in(key(42), 1) -> eps key

  dssm_main<<<NWG, NTHR, 0, stream>>>(gx, gy,
      pW1, pb1, pW2, pb2, pW3, pb3,
      qW1, qb1, qW2, qb2, qW3, qb3,
      eW1, eb1, eW2, eb2, eW3, eb3,
      z0mu, z0lv, gout, gws, ka0, ka1, kb0, kb1);
  dssm_fin<<<1, 256, 0, stream>>>(gws, gout);
}